// Round 2
// baseline (568.450 us; speedup 1.0000x reference)
//
#include <hip/hip_runtime.h>

typedef _Float16 f16;
typedef _Float16 f16x8 __attribute__((ext_vector_type(8)));
typedef float f32x4 __attribute__((ext_vector_type(4)));
typedef unsigned short u16;
typedef unsigned int u32;

// ---------- conversions ----------
__device__ __forceinline__ float bf2f(u16 b) {
  union { u32 u; float f; } t; t.u = ((u32)b) << 16; return t.f;
}
__device__ __forceinline__ u16 f2bf(float f) {  // RNE float->bf16 bits
  union { float f; u32 u; } t; t.f = f;
  u32 u = t.u;
  return (u16)((u + 0x7FFFu + ((u >> 16) & 1u)) >> 16);
}
__device__ __forceinline__ u16 f2h_bits(float f) {
  f16 h = (f16)f;
  union { f16 h; u16 u; } t; t.h = h; return t.u;
}
__device__ __forceinline__ float2 up2(u32 p) {  // f16 pair -> float2
  union { u32 u; f16 h[2]; } t; t.u = p;
  float2 r; r.x = (float)t.h[0]; r.y = (float)t.h[1]; return r;
}
__device__ __forceinline__ u32 pk2(float x, float y) {  // float2 -> f16 pair
  return (u32)f2h_bits(x) | ((u32)f2h_bits(y) << 16);
}

// ---------------- dtype detection (standalone, canary path only) ----------------
__global__ void k_detect(const u16* __restrict__ elemRaw, const int* __restrict__ eiRaw,
                         int* __restrict__ dflags) {
  __shared__ int bad, nzOdd;
  if (threadIdx.x == 0) { bad = 0; nzOdd = 0; }
  __syncthreads();
  int myBad = 0;
  for (int i = threadIdx.x; i < 4096; i += 256) {
    float v = bf2f(elemRaw[i]);
    if (!(v > -0.2f && v < 0.2f)) myBad++;
  }
  if (myBad) atomicAdd(&bad, myBad);
  int myNz = 0;
  for (int i = threadIdx.x; i < 1024; i += 256)
    if (eiRaw[2 * i + 1] != 0) myNz++;  // int64 high words would be 0
  if (myNz) atomicAdd(&nzOdd, myNz);
  __syncthreads();
  if (threadIdx.x == 0) {
    dflags[0] = (bad == 0) ? 1 : 0;
    dflags[1] = (nzOdd > 16) ? 1 : 0;
  }
}

// ---------------- merged detect + zero ----------------
__global__ void k_init(const u16* __restrict__ elemRaw, const int* __restrict__ eiRaw,
                       int* __restrict__ dflags, int* __restrict__ counts,
                       float* __restrict__ stats, int NPad) {
  if (blockIdx.x == 0) {
    __shared__ int bad, nzOdd;
    if (threadIdx.x == 0) { bad = 0; nzOdd = 0; }
    __syncthreads();
    int myBad = 0;
    for (int i = threadIdx.x; i < 4096; i += 256) {
      float v = bf2f(elemRaw[i]);
      if (!(v > -0.2f && v < 0.2f)) myBad++;
    }
    if (myBad) atomicAdd(&bad, myBad);
    int myNz = 0;
    for (int i = threadIdx.x; i < 1024; i += 256)
      if (eiRaw[2 * i + 1] != 0) myNz++;
    if (myNz) atomicAdd(&nzOdd, myNz);
    __syncthreads();
    if (threadIdx.x == 0) {
      dflags[0] = (bad == 0) ? 1 : 0;
      dflags[1] = (nzOdd > 16) ? 1 : 0;
    }
  } else {
    int i = (blockIdx.x - 1) * 256 + threadIdx.x;
    if (i < NPad) counts[i] = 0;
    else if (i < NPad + 1280) stats[i - NPad] = 0.f;
  }
}

__global__ void k_canary(u32* __restrict__ out, const int* __restrict__ dflags,
                         int out_size, u32 pBf, u32 pF32) {
  int isbf = dflags[0];
  int words = isbf ? (out_size >> 1) : out_size;
  int i = blockIdx.x * 256 + threadIdx.x;
  if (i < words) out[i] = isbf ? pBf : pF32;
}

// ---------------- combined canonicalize (+fused dst histogram) ----------------
__global__ void k_cvt(const int* __restrict__ xR, const int* __restrict__ eiR,
                      const int* __restrict__ eaR,
                      const u16* e0, const u16* e1, const u16* e2, const u16* e3,
                      const u16* e4, const u16* e5, const u16* e6, const u16* e7,
                      const u16* e8, const u16* e9,
                      const int* __restrict__ dflags,
                      int* __restrict__ x32, int* __restrict__ ei32, int* __restrict__ combo,
                      int* __restrict__ counts, float* __restrict__ dst,
                      int N, int E, int intBlocks) {
  if ((int)blockIdx.x < intBlocks) {
    int pi = blockIdx.x * 256 + threadIdx.x;
    int nPairs = N + 2 * E;
    if (pi >= nPairs) return;
    int is32 = dflags[1];
    const int* src; int local; int kind;
    if (pi < N) { src = xR; local = pi; kind = 0; }
    else if (pi < N + E) { src = eiR; local = pi - N; kind = 1; }
    else { src = eaR; local = pi - N - E; kind = 2; }
    int j0 = 2 * local;
    int v0, v1;
    if (is32) { int2 v = *(const int2*)(src + j0); v0 = v.x; v1 = v.y; }
    else      { int4 v = *(const int4*)(src + 2 * j0); v0 = v.x; v1 = v.z; }
    if (kind == 0) { x32[j0] = v0; x32[j0 + 1] = v1; }
    else if (kind == 1) {
      ei32[j0] = v0; ei32[j0 + 1] = v1;
      if (j0 >= E) {  // dst half
        atomicAdd(&counts[v0], 1);
        atomicAdd(&counts[v1], 1);
      }
    } else {
      combo[local] = v0 * 3 + v1;
    }
  } else {
    int i = (blockIdx.x - intBlocks) * 256 + threadIdx.x;
    if (i >= 83712) return;
    int isbf = dflags[0];
    const u16* src; int j;
    if      (i < 15104) { src = e0; j = i; }
    else if (i < 15616) { src = e1; j = i - 15104; }
    else if (i < 16128) { src = e2; j = i - 15616; }
    else if (i < 16512) { src = e3; j = i - 16128; }
    else if (i < 49280) { src = e4; j = i - 16512; }
    else if (i < 49536) { src = e5; j = i - 49280; }
    else if (i < 82304) { src = e6; j = i - 49536; }
    else if (i < 82432) { src = e7; j = i - 82304; }
    else if (i < 83072) { src = e8; j = i - 82432; }
    else                { src = e9; j = i - 83072; }
    dst[i] = isbf ? bf2f(src[j]) : ((const float*)src)[j];
  }
}

// ---------------- CSR scan ----------------
__global__ void k_chunksum(const int* __restrict__ counts, int* __restrict__ bsum) {
  int tid = threadIdx.x, lane = tid & 63, w = tid >> 6;
  const int4* c4 = (const int4*)(counts + blockIdx.x * 1024);
  int4 v = c4[tid];
  int s = v.x + v.y + v.z + v.w;
#pragma unroll
  for (int d = 1; d < 64; d <<= 1) s += __shfl_xor(s, d);
  __shared__ int ws[4];
  if (lane == 0) ws[w] = s;
  __syncthreads();
  if (tid == 0) bsum[blockIdx.x] = ws[0] + ws[1] + ws[2] + ws[3];
}

__global__ void k_chunkscan(const int* __restrict__ bsum, int* __restrict__ boff,
                            int* __restrict__ row_start, int N, int nCh) {
  int t = threadIdx.x;
  int v = (t < nCh) ? bsum[t] : 0;
  int incl = v;
#pragma unroll
  for (int d = 1; d < 64; d <<= 1) { int tmp = __shfl_up(incl, d); if (t >= d) incl += tmp; }
  boff[t] = incl - v;
  if (t == 63) row_start[N] = incl;  // = E
}

__global__ void k_scanapply(const int* __restrict__ counts, const int* __restrict__ boff,
                            int* __restrict__ row_start, int* __restrict__ cursor, int N) {
  int tid = threadIdx.x, lane = tid & 63, w = tid >> 6;
  int base = blockIdx.x * 1024 + tid * 4;
  int4 v = *(const int4*)(counts + base);
  int tsum = v.x + v.y + v.z + v.w;
  int incl = tsum;
#pragma unroll
  for (int d = 1; d < 64; d <<= 1) { int tmp = __shfl_up(incl, d); if (lane >= d) incl += tmp; }
  __shared__ int ws[4];
  if (lane == 63) ws[w] = incl;
  __syncthreads();
  int woff = 0;
  for (int j = 0; j < w; ++j) woff += ws[j];
  int excl = boff[blockIdx.x] + woff + incl - tsum;
  int e0 = excl, e1 = excl + v.x, e2 = e1 + v.y, e3 = e2 + v.z;
  if (base < N)     { row_start[base] = e0;     cursor[base] = e0; }
  if (base + 1 < N) { row_start[base + 1] = e1; cursor[base + 1] = e1; }
  if (base + 2 < N) { row_start[base + 2] = e2; cursor[base + 2] = e2; }
  if (base + 3 < N) { row_start[base + 3] = e3; cursor[base + 3] = e3; }
}

__global__ void k_scatter(const int* __restrict__ ei, const int* __restrict__ combo,
                          int* cursor, int* packed, int E) {
  int e = blockIdx.x * blockDim.x + threadIdx.x;
  if (e >= E) return;
  int s = ei[e], d = ei[E + e];
  int cb = combo[e];
  int pos = atomicAdd(&cursor[d], 1);
  packed[pos] = s | (cb << 20);  // src < 2^20, combo in [0,12)
}

// ---------------- fragment-ordered weights + bond table + h0 (merged) ----------------
__global__ void k_prep(const float* __restrict__ cflt, const int* __restrict__ x,
                       u32* __restrict__ W1F, u32* __restrict__ W2F,
                       u32* __restrict__ tblC, u32* __restrict__ hb, int N, int wtBlocks) {
  if ((int)blockIdx.x < wtBlocks) {
    const float* W1 = cflt + 16512;   // [128][256] row-major (k, n)
    const float* W2 = cflt + 49536;   // [256][128] row-major (k2, n2)
    const float* bt = cflt + 15616;
    const float* bd = cflt + 16128;
    int g = blockIdx.x * 256 + threadIdx.x;  // 0..16383 (one u32 of each table)
    {
      int e = g >> 2, wd = g & 3;
      int lane = e & 63, nt = (e >> 6) & 3, ks = (e >> 8) & 3, c = (e >> 10) & 3;
      int q = lane >> 4, lo = lane & 15;
      int n = c * 64 + nt * 16 + lo;
      int k0 = (ks * 4 + q) * 8 + wd * 2;
      W1F[g] = pk2(W1[k0 * 256 + n], W1[(k0 + 1) * 256 + n]);
    }
    {
      int e = g >> 2, wd = g & 3;
      int lane = e & 63, nt = (e >> 6) & 7, ks2 = (e >> 9) & 1, c = (e >> 10) & 3;
      int q = lane >> 4, lo = lane & 15;
      int n2 = nt * 16 + lo;
      int k20 = c * 64 + (ks2 * 4 + q) * 8 + wd * 2;
      W2F[g] = pk2(W2[k20 * 128 + n2], W2[(k20 + 1) * 128 + n2]);
    }
    if (g < 768) {
      int combo = g >> 6, l = g & 63, c0 = l * 2;
      int a0 = combo / 3, a1 = combo - a0 * 3;
      tblC[g] = pk2(bt[a0 * 128 + c0] + bd[a1 * 128 + c0],
                    bt[a0 * 128 + c0 + 1] + bd[a1 * 128 + c0 + 1]);
    }
  } else {
    const float* elem = cflt;
    const float* chir = cflt + 15104;
    int b = blockIdx.x - wtBlocks;
    int wv = (int)(threadIdx.x >> 6);
    int lane = threadIdx.x & 63;
    int node = b * 4 + wv;
    if (node >= N) return;
    int x0 = x[node * 2], x1 = x[node * 2 + 1];
    int c0 = lane * 2;
    float vx = elem[x0 * 128 + c0] + chir[x1 * 128 + c0];
    float vy = elem[x0 * 128 + c0 + 1] + chir[x1 * 128 + c0 + 1];
    hb[(size_t)node * 64 + lane] = pk2(vx, vy);
  }
}

// ---------------- gather/aggregate: ONE node per wave, 64 lanes x 4B (2 channels) ----
// BN=false: hsrc holds h directly (layer 0: h0).
// BN=true:  hsrc holds raw MLP output 'act'; h = relu(act*sc + sh) on the fly
//           (only 2 channels/lane -> 4 extra VALU ops per edge, hidden under gather BW).
// Edges processed in masked chunks of 8: all 8 gathers issued (clamped index),
// accumulation predicated -> no serial tail, no sub-chain imbalance.
template <bool BN>
__global__ __launch_bounds__(256) void k_agg(
    const u32* __restrict__ hsrc, const int* __restrict__ row_start,
    const int* __restrict__ packed, const u32* __restrict__ tblC,
    const float* __restrict__ statsL, const float* __restrict__ gamma,
    const float* __restrict__ beta, float invN,
    u32* __restrict__ z, int N) {
  __shared__ u32 tbl[768];  // [combo][64 u32]
  __shared__ float ssc[128], ssh[128];
  for (int idx = threadIdx.x; idx < 768; idx += 256) tbl[idx] = tblC[idx];
  if (BN && threadIdx.x < 128) {
    int c = threadIdx.x;
    float mean = statsL[c] * invN;
    float var = statsL[128 + c] * invN - mean * mean;
    float inv = rsqrtf(var + 1e-5f);
    float scv = gamma[c] * inv;
    ssc[c] = scv;
    ssh[c] = beta[c] - mean * scv;
  }
  __syncthreads();
  const int w = threadIdx.x >> 6, lane = threadIdx.x & 63;
  const int node = blockIdx.x * 4 + w;
  if (node >= N) return;
  float scx, scy, shx, shy;
  if (BN) {
    scx = ssc[2 * lane]; scy = ssc[2 * lane + 1];
    shx = ssh[2 * lane]; shy = ssh[2 * lane + 1];
  }
  float ax, ay;
  {
    float2 sv = up2(hsrc[(size_t)node * 64 + lane]);
    if (BN) {
      sv.x = fmaxf(fmaf(sv.x, scx, shx), 0.f);
      sv.y = fmaxf(fmaf(sv.y, scy, shy), 0.f);
    }
    ax = sv.x; ay = sv.y;
  }
  const int s_ = row_start[node], e_ = row_start[node + 1];
  for (int p = s_; p < e_; p += 8) {
    int kk[8]; u32 rr[8], tt[8];
#pragma unroll
    for (int j = 0; j < 8; ++j)
      kk[j] = packed[(p + j < e_) ? (p + j) : (e_ - 1)];
#pragma unroll
    for (int j = 0; j < 8; ++j)
      rr[j] = hsrc[(size_t)(kk[j] & 0xFFFFF) * 64 + lane];
#pragma unroll
    for (int j = 0; j < 8; ++j)
      tt[j] = tbl[(kk[j] >> 20) * 64 + lane];
#pragma unroll
    for (int j = 0; j < 8; ++j) {
      if (p + j < e_) {
        float2 rv = up2(rr[j]);
        float2 tv = up2(tt[j]);
        float hx, hy;
        if (BN) {
          hx = fmaxf(fmaf(rv.x, scx, shx), 0.f);
          hy = fmaxf(fmaf(rv.y, scy, shy), 0.f);
        } else { hx = rv.x; hy = rv.y; }
        ax += fmaxf(hx + tv.x, 0.f);
        ay += fmaxf(hy + tv.y, 0.f);
      }
    }
  }
  z[(size_t)node * 64 + lane] = pk2(ax, ay);
}

// ---------------- persistent MLP: weights LDS-resident, 12 waves, single round -------
__global__ __launch_bounds__(768, 1) void k_mlp(
    const u16* __restrict__ z, const u32* __restrict__ W1F, const u32* __restrict__ W2F,
    const float* __restrict__ b1, const float* __restrict__ b2,
    u16* __restrict__ act, float* __restrict__ statsL, int N, int nTiles) {
  __shared__ u32 sW1[16384];      // 64 KB fragment-ordered W1
  __shared__ u32 sW2[16384];      // 64 KB fragment-ordered W2
  __shared__ u16 sYp[12][1024];   // 24 KB: per-wave private Y (16x64, swizzled)
  __shared__ float sStats[256];   // 1 KB
  __shared__ float sB1[256];      // 1 KB biases (keeps VGPR under the 3-wave/SIMD cap)
  __shared__ float sB2[128];      // 0.5 KB

  const int tid = threadIdx.x;
  const int w = tid >> 6, lane = tid & 63;
  const int lo = lane & 15, q = lane >> 4;

  if (tid < 256) { sStats[tid] = 0.f; sB1[tid] = b1[tid]; }
  if (tid < 128) sB2[tid] = b2[tid];
  {
    const int4* gW1 = (const int4*)W1F;
    const int4* gW2 = (const int4*)W2F;
    int4* lW1 = (int4*)sW1;
    int4* lW2 = (int4*)sW2;
    for (int o = tid; o < 4096; o += 768) {
      lW1[o] = gW1[o];
      lW2[o] = gW2[o];
    }
  }
  __syncthreads();

  float aSum[8] = {}, aSq[8] = {};
  u16* myY = sYp[w];

  for (int t = blockIdx.x * 12 + w; t < nTiles; t += 3072) {
    const int row0 = t * 16;
    f16x8 a1[4];
    const char* zrow = (const char*)z + (size_t)(row0 + lo) * 256;
#pragma unroll
    for (int ks = 0; ks < 4; ++ks)
      a1[ks] = *(const f16x8*)(zrow + (ks * 4 + q) * 16);

    f32x4 accO[8] = {};
#pragma unroll
    for (int c = 0; c < 4; ++c) {
      f16x8 B1[16];
#pragma unroll
      for (int i = 0; i < 16; ++i)
        B1[i] = *(const f16x8*)((const char*)sW1 + ((c * 16 + i) << 10) + lane * 16);
      f32x4 acc1[4] = {};
#pragma unroll
      for (int ks = 0; ks < 4; ++ks)
#pragma unroll
        for (int nt = 0; nt < 4; ++nt)
          acc1[nt] = __builtin_amdgcn_mfma_f32_16x16x32_f16(a1[ks], B1[ks * 4 + nt], acc1[nt], 0, 0, 0);
#pragma unroll
      for (int nt = 0; nt < 4; ++nt) {
        int ycol = nt * 16 + lo;
        float bias = sB1[c * 64 + nt * 16 + lo];
#pragma unroll
        for (int i = 0; i < 4; ++i) {
          int m = q * 4 + i;
          float v = fmaxf(acc1[nt][i] + bias, 0.f);
          myY[m * 64 + (((ycol >> 3) ^ (m & 7)) << 3) + (ycol & 7)] = f2h_bits(v);
        }
      }
      f16x8 B2[16];
#pragma unroll
      for (int i = 0; i < 16; ++i)
        B2[i] = *(const f16x8*)((const char*)sW2 + ((c * 16 + i) << 10) + lane * 16);
#pragma unroll
      for (int ks2 = 0; ks2 < 2; ++ks2) {
        int kq2 = ks2 * 4 + q;
        f16x8 a2 = *(const f16x8*)(myY + lo * 64 + ((kq2 ^ (lo & 7)) << 3));
#pragma unroll
        for (int nt = 0; nt < 8; ++nt)
          accO[nt] = __builtin_amdgcn_mfma_f32_16x16x32_f16(a2, B2[ks2 * 8 + nt], accO[nt], 0, 0, 0);
      }
    }
#pragma unroll
    for (int nt = 0; nt < 8; ++nt) {
      int n2 = nt * 16 + lo;
      float bias = sB2[nt * 16 + lo];
#pragma unroll
      for (int i = 0; i < 4; ++i) {
        int row = row0 + q * 4 + i;
        float v = accO[nt][i] + bias;
        act[(size_t)row * 128 + n2] = f2h_bits(v);
        if (row < N) { aSum[nt] += v; aSq[nt] += v * v; }
      }
    }
  }

#pragma unroll
  for (int nt = 0; nt < 8; ++nt) {
    float s = aSum[nt], s2 = aSq[nt];
    s += __shfl_xor(s, 16); s += __shfl_xor(s, 32);
    s2 += __shfl_xor(s2, 16); s2 += __shfl_xor(s2, 32);
    if (q == 0) {
      atomicAdd(&sStats[nt * 16 + lo], s);
      atomicAdd(&sStats[128 + nt * 16 + lo], s2);
    }
  }
  __syncthreads();
  if (tid < 256) atomicAdd(&statsL[tid], sStats[tid]);
}

// ---------------- final: BN (no relu) -> output dtype ----------------
__global__ __launch_bounds__(256) void k_final(
    const u32* __restrict__ act, const float* __restrict__ statsL,
    const float* __restrict__ gamma, const float* __restrict__ beta,
    float invN, const int* __restrict__ dflags, void* __restrict__ outv, int N) {
  __shared__ float ssc[128], ssh[128];
  int tid = threadIdx.x;
  if (tid < 128) {
    float mean = statsL[tid] * invN;
    float var = statsL[128 + tid] * invN - mean * mean;
    float inv = rsqrtf(var + 1e-5f);
    float scv = gamma[tid] * inv;
    ssc[tid] = scv;
    ssh[tid] = beta[tid] - mean * scv;
  }
  __syncthreads();
  int isbf = dflags[0];
  int total = N * 64;
  for (int i = blockIdx.x * 256 + tid; i < total; i += gridDim.x * 256) {
    int c0 = (i & 63) * 2;
    float2 v = up2(act[i]);
    float ox = v.x * ssc[c0] + ssh[c0];
    float oy = v.y * ssc[c0 + 1] + ssh[c0 + 1];
    if (isbf) ((u32*)outv)[i] = (u32)f2bf(ox) | ((u32)f2bf(oy) << 16);
    else { float2 o; o.x = ox; o.y = oy; ((float2*)outv)[i] = o; }
  }
}

extern "C" void kernel_launch(void* const* d_in, const int* in_sizes, int n_in,
                              void* d_out, int out_size, void* d_ws, size_t ws_size,
                              hipStream_t stream) {
  const int* xR  = (const int*)d_in[0];
  const int* eiR = (const int*)d_in[1];
  const int* eaR = (const int*)d_in[2];
  const u16* emR = (const u16*)d_in[3];
  const u16* chR = (const u16*)d_in[4];
  const u16* btR = (const u16*)d_in[5];
  const u16* bdR = (const u16*)d_in[6];
  const u16* W1R = (const u16*)d_in[7];
  const u16* b1R = (const u16*)d_in[8];
  const u16* W2R = (const u16*)d_in[9];
  const u16* b2R = (const u16*)d_in[10];
  const u16* gR  = (const u16*)d_in[11];
  const u16* beR = (const u16*)d_in[12];

  const int N = in_sizes[0] / 2;      // 50000
  const int E = in_sizes[1] / 2;      // 600000
  const int L = in_sizes[11] / 128;   // 5
  const int Mpad = ((N + 63) / 64) * 64;
  const int nCh = (N + 1023) / 1024;
  const int NPad = nCh * 1024;
  const int nTiles = (N + 15) / 16;   // 3125

  char* base = (char*)d_ws;
  size_t off = 0;
  auto take = [&](size_t bytes) -> void* {
    void* p = base + off;
    off += (bytes + 255) & ~(size_t)255;
    return p;
  };
  int*   dflags    = (int*)  take(256);
  int*   x32       = (int*)  take((size_t)2 * N * 4);
  int*   ei32      = (int*)  take((size_t)2 * E * 4);
  int*   combo     = (int*)  take((size_t)E * 4);
  float* cflt      = (float*)take(83712 * 4);
  u32*   act       = (u32*)  take((size_t)Mpad * 64 * 4);   // raw MLP out (f16 pairs)
  u32*   hb        = (u32*)  take((size_t)Mpad * 64 * 4);   // h0 (layer-0 input)
  u16*   zb        = (u16*)  take((size_t)Mpad * 128 * 2);
  int*   packed    = (int*)  take((size_t)E * 4);
  int*   row_start = (int*)  take((size_t)(N + 1) * 4);
  int*   cursor    = (int*)  take((size_t)N * 4);
  int*   counts    = (int*)  take((size_t)NPad * 4);
  int*   bsum      = (int*)  take(64 * 4);
  int*   boff      = (int*)  take(64 * 4);
  float* stats     = (float*)take((size_t)L * 256 * 4);
  u32*   W1F       = (u32*)  take(16384 * 4);
  u32*   W2F       = (u32*)  take(16384 * 4);
  u32*   tblC      = (u32*)  take(768 * 4);
  const size_t need = off;
  (void)n_in;

  float* cB1 = cflt + 49280;
  float* cB2 = cflt + 82304;
  float* cGamma = cflt + 82432;
  float* cBeta = cflt + 83072;

  if (need > ws_size) {
    k_detect<<<dim3(1), dim3(256), 0, stream>>>(emR, eiR, dflags);
    k_canary<<<dim3((out_size + 255) / 256), dim3(256), 0, stream>>>(
        (u32*)d_out, dflags, out_size, 0x40004000u, 0x40000000u);
    return;
  }

  // merged detect + zero(counts, stats)
  const int nzBlocks = (NPad + 1280 + 255) / 256;
  k_init<<<dim3(nzBlocks + 1), dim3(256), 0, stream>>>(emR, eiR, dflags, counts, stats, NPad);

  const int nPairs = N + 2 * E;
  const int intBlocks = (nPairs + 255) / 256;
  const int fltBlocks = (83712 + 255) / 256;
  k_cvt<<<dim3(intBlocks + fltBlocks), dim3(256), 0, stream>>>(
      xR, eiR, eaR, emR, chR, btR, bdR, W1R, b1R, W2R, b2R, gR, beR,
      dflags, x32, ei32, combo, counts, cflt, N, E, intBlocks);

  k_chunksum<<<dim3(nCh), dim3(256), 0, stream>>>(counts, bsum);
  k_chunkscan<<<dim3(1), dim3(64), 0, stream>>>(bsum, boff, row_start, N, nCh);
  k_scanapply<<<dim3(nCh), dim3(256), 0, stream>>>(counts, boff, row_start, cursor, N);
  k_scatter<<<dim3((E + 255) / 256), dim3(256), 0, stream>>>(ei32, combo, cursor, packed, E);

  const int wtBlocks = 64;  // 16384 threads for W1F/W2F words
  k_prep<<<dim3(wtBlocks + (N + 3) / 4), dim3(256), 0, stream>>>(
      cflt, x32, W1F, W2F, tblC, hb, N, wtBlocks);

  const float invN = 1.0f / (float)N;
  for (int l = 0; l < L; ++l) {
    if (l == 0) {
      k_agg<false><<<dim3((N + 3) / 4), dim3(256), 0, stream>>>(
          hb, row_start, packed, tblC, nullptr, nullptr, nullptr, 0.f, (u32*)zb, N);
    } else {
      k_agg<true><<<dim3((N + 3) / 4), dim3(256), 0, stream>>>(
          act, row_start, packed, tblC, stats + (size_t)(l - 1) * 256,
          cGamma + (size_t)(l - 1) * 128, cBeta + (size_t)(l - 1) * 128, invN,
          (u32*)zb, N);
    }
    k_mlp<<<dim3(256), dim3(768), 0, stream>>>(
        zb, W1F, W2F, cB1, cB2, (u16*)act, stats + (size_t)l * 256, N, nTiles);
  }
  k_final<<<dim3(1024), dim3(256), 0, stream>>>(
      act, stats + (size_t)(L - 1) * 256, cGamma + (size_t)(L - 1) * 128,
      cBeta + (size_t)(L - 1) * 128, invN, dflags, d_out, N);
}

// Round 3
// 550.092 us; speedup vs baseline: 1.0334x; 1.0334x over previous
//
#include <hip/hip_runtime.h>

typedef _Float16 f16;
typedef _Float16 f16x8 __attribute__((ext_vector_type(8)));
typedef _Float16 h2 __attribute__((ext_vector_type(2)));
typedef float f32x4 __attribute__((ext_vector_type(4)));
typedef unsigned short u16;
typedef unsigned int u32;

// ---------- conversions ----------
__device__ __forceinline__ float bf2f(u16 b) {
  union { u32 u; float f; } t; t.u = ((u32)b) << 16; return t.f;
}
__device__ __forceinline__ u16 f2bf(float f) {  // RNE float->bf16 bits
  union { float f; u32 u; } t; t.f = f;
  u32 u = t.u;
  return (u16)((u + 0x7FFFu + ((u >> 16) & 1u)) >> 16);
}
__device__ __forceinline__ u16 f2h_bits(float f) {
  f16 h = (f16)f;
  union { f16 h; u16 u; } t; t.h = h; return t.u;
}
__device__ __forceinline__ float2 up2(u32 p) {  // f16 pair -> float2
  union { u32 u; f16 h[2]; } t; t.u = p;
  float2 r; r.x = (float)t.h[0]; r.y = (float)t.h[1]; return r;
}
__device__ __forceinline__ u32 pk2(float x, float y) {  // float2 -> f16 pair
  return (u32)f2h_bits(x) | ((u32)f2h_bits(y) << 16);
}
__device__ __forceinline__ h2 asH2(u32 u) {
  union { u32 u; h2 h; } t; t.u = u; return t.h;
}
__device__ __forceinline__ h2 relu2(h2 a) {
#if __has_builtin(__builtin_elementwise_max)
  h2 z = {(_Float16)0, (_Float16)0};
  return __builtin_elementwise_max(a, z);
#else
  h2 r;
  r.x = a.x > (_Float16)0 ? a.x : (_Float16)0;
  r.y = a.y > (_Float16)0 ? a.y : (_Float16)0;
  return r;
#endif
}

// ---------------- dtype detection (standalone, canary path only) ----------------
__global__ void k_detect(const u16* __restrict__ elemRaw, const int* __restrict__ eiRaw,
                         int* __restrict__ dflags) {
  __shared__ int bad, nzOdd;
  if (threadIdx.x == 0) { bad = 0; nzOdd = 0; }
  __syncthreads();
  int myBad = 0;
  for (int i = threadIdx.x; i < 4096; i += 256) {
    float v = bf2f(elemRaw[i]);
    if (!(v > -0.2f && v < 0.2f)) myBad++;
  }
  if (myBad) atomicAdd(&bad, myBad);
  int myNz = 0;
  for (int i = threadIdx.x; i < 1024; i += 256)
    if (eiRaw[2 * i + 1] != 0) myNz++;  // int64 high words would be 0
  if (myNz) atomicAdd(&nzOdd, myNz);
  __syncthreads();
  if (threadIdx.x == 0) {
    dflags[0] = (bad == 0) ? 1 : 0;
    dflags[1] = (nzOdd > 16) ? 1 : 0;
  }
}

// ---------------- merged detect + zero (counts only; stats needs no zeroing) --------
__global__ void k_init(const u16* __restrict__ elemRaw, const int* __restrict__ eiRaw,
                       int* __restrict__ dflags, int* __restrict__ counts, int NPad) {
  if (blockIdx.x == 0) {
    __shared__ int bad, nzOdd;
    if (threadIdx.x == 0) { bad = 0; nzOdd = 0; }
    __syncthreads();
    int myBad = 0;
    for (int i = threadIdx.x; i < 4096; i += 256) {
      float v = bf2f(elemRaw[i]);
      if (!(v > -0.2f && v < 0.2f)) myBad++;
    }
    if (myBad) atomicAdd(&bad, myBad);
    int myNz = 0;
    for (int i = threadIdx.x; i < 1024; i += 256)
      if (eiRaw[2 * i + 1] != 0) myNz++;
    if (myNz) atomicAdd(&nzOdd, myNz);
    __syncthreads();
    if (threadIdx.x == 0) {
      dflags[0] = (bad == 0) ? 1 : 0;
      dflags[1] = (nzOdd > 16) ? 1 : 0;
    }
  } else {
    int i = (blockIdx.x - 1) * 256 + threadIdx.x;
    if (i < NPad) counts[i] = 0;
  }
}

__global__ void k_canary(u32* __restrict__ out, const int* __restrict__ dflags,
                         int out_size, u32 pBf, u32 pF32) {
  int isbf = dflags[0];
  int words = isbf ? (out_size >> 1) : out_size;
  int i = blockIdx.x * 256 + threadIdx.x;
  if (i < words) out[i] = isbf ? pBf : pF32;
}

// ---------------- combined canonicalize (+fused dst histogram) ----------------
__global__ void k_cvt(const int* __restrict__ xR, const int* __restrict__ eiR,
                      const int* __restrict__ eaR,
                      const u16* e0, const u16* e1, const u16* e2, const u16* e3,
                      const u16* e4, const u16* e5, const u16* e6, const u16* e7,
                      const u16* e8, const u16* e9,
                      const int* __restrict__ dflags,
                      int* __restrict__ x32, int* __restrict__ ei32, int* __restrict__ combo,
                      int* __restrict__ counts, float* __restrict__ dst,
                      int N, int E, int intBlocks) {
  if ((int)blockIdx.x < intBlocks) {
    int pi = blockIdx.x * 256 + threadIdx.x;
    int nPairs = N + 2 * E;
    if (pi >= nPairs) return;
    int is32 = dflags[1];
    const int* src; int local; int kind;
    if (pi < N) { src = xR; local = pi; kind = 0; }
    else if (pi < N + E) { src = eiR; local = pi - N; kind = 1; }
    else { src = eaR; local = pi - N - E; kind = 2; }
    int j0 = 2 * local;
    int v0, v1;
    if (is32) { int2 v = *(const int2*)(src + j0); v0 = v.x; v1 = v.y; }
    else      { int4 v = *(const int4*)(src + 2 * j0); v0 = v.x; v1 = v.z; }
    if (kind == 0) { x32[j0] = v0; x32[j0 + 1] = v1; }
    else if (kind == 1) {
      ei32[j0] = v0; ei32[j0 + 1] = v1;
      if (j0 >= E) {  // dst half
        atomicAdd(&counts[v0], 1);
        atomicAdd(&counts[v1], 1);
      }
    } else {
      combo[local] = v0 * 3 + v1;
    }
  } else {
    int i = (blockIdx.x - intBlocks) * 256 + threadIdx.x;
    if (i >= 83712) return;
    int isbf = dflags[0];
    const u16* src; int j;
    if      (i < 15104) { src = e0; j = i; }
    else if (i < 15616) { src = e1; j = i - 15104; }
    else if (i < 16128) { src = e2; j = i - 15616; }
    else if (i < 16512) { src = e3; j = i - 16128; }
    else if (i < 49280) { src = e4; j = i - 16512; }
    else if (i < 49536) { src = e5; j = i - 49280; }
    else if (i < 82304) { src = e6; j = i - 49536; }
    else if (i < 82432) { src = e7; j = i - 82304; }
    else if (i < 83072) { src = e8; j = i - 82432; }
    else                { src = e9; j = i - 83072; }
    dst[i] = isbf ? bf2f(src[j]) : ((const float*)src)[j];
  }
}

// ---------------- CSR scan ----------------
__global__ void k_chunksum(const int* __restrict__ counts, int* __restrict__ bsum) {
  int tid = threadIdx.x, lane = tid & 63, w = tid >> 6;
  const int4* c4 = (const int4*)(counts + blockIdx.x * 1024);
  int4 v = c4[tid];
  int s = v.x + v.y + v.z + v.w;
#pragma unroll
  for (int d = 1; d < 64; d <<= 1) s += __shfl_xor(s, d);
  __shared__ int ws[4];
  if (lane == 0) ws[w] = s;
  __syncthreads();
  if (tid == 0) bsum[blockIdx.x] = ws[0] + ws[1] + ws[2] + ws[3];
}

__global__ void k_chunkscan(const int* __restrict__ bsum, int* __restrict__ boff,
                            int* __restrict__ row_start, int N, int nCh) {
  int t = threadIdx.x;
  int v = (t < nCh) ? bsum[t] : 0;
  int incl = v;
#pragma unroll
  for (int d = 1; d < 64; d <<= 1) { int tmp = __shfl_up(incl, d); if (t >= d) incl += tmp; }
  boff[t] = incl - v;
  if (t == 63) row_start[N] = incl;  // = E
}

__global__ void k_scanapply(const int* __restrict__ counts, const int* __restrict__ boff,
                            int* __restrict__ row_start, int* __restrict__ cursor, int N) {
  int tid = threadIdx.x, lane = tid & 63, w = tid >> 6;
  int base = blockIdx.x * 1024 + tid * 4;
  int4 v = *(const int4*)(counts + base);
  int tsum = v.x + v.y + v.z + v.w;
  int incl = tsum;
#pragma unroll
  for (int d = 1; d < 64; d <<= 1) { int tmp = __shfl_up(incl, d); if (lane >= d) incl += tmp; }
  __shared__ int ws[4];
  if (lane == 63) ws[w] = incl;
  __syncthreads();
  int woff = 0;
  for (int j = 0; j < w; ++j) woff += ws[j];
  int excl = boff[blockIdx.x] + woff + incl - tsum;
  int e0 = excl, e1 = excl + v.x, e2 = e1 + v.y, e3 = e2 + v.z;
  if (base < N)     { row_start[base] = e0;     cursor[base] = e0; }
  if (base + 1 < N) { row_start[base + 1] = e1; cursor[base + 1] = e1; }
  if (base + 2 < N) { row_start[base + 2] = e2; cursor[base + 2] = e2; }
  if (base + 3 < N) { row_start[base + 3] = e3; cursor[base + 3] = e3; }
}

__global__ void k_scatter(const int* __restrict__ ei, const int* __restrict__ combo,
                          int* cursor, int* packed, int E) {
  int e = blockIdx.x * blockDim.x + threadIdx.x;
  if (e >= E) return;
  int s = ei[e], d = ei[E + e];
  int cb = combo[e];
  int pos = atomicAdd(&cursor[d], 1);
  packed[pos] = s | (cb << 20);  // src < 2^20, combo in [0,12)
}

// ---------------- fragment-ordered weights + bond table + h0 (merged) ----------------
__global__ void k_prep(const float* __restrict__ cflt, const int* __restrict__ x,
                       u32* __restrict__ W1F, u32* __restrict__ W2F,
                       u32* __restrict__ tblC, u32* __restrict__ hb, int N, int wtBlocks) {
  if ((int)blockIdx.x < wtBlocks) {
    const float* W1 = cflt + 16512;   // [128][256] row-major (k, n)
    const float* W2 = cflt + 49536;   // [256][128] row-major (k2, n2)
    const float* bt = cflt + 15616;
    const float* bd = cflt + 16128;
    int g = blockIdx.x * 256 + threadIdx.x;  // 0..16383 (one u32 of each table)
    {
      int e = g >> 2, wd = g & 3;
      int lane = e & 63, nt = (e >> 6) & 3, ks = (e >> 8) & 3, c = (e >> 10) & 3;
      int q = lane >> 4, lo = lane & 15;
      int n = c * 64 + nt * 16 + lo;
      int k0 = (ks * 4 + q) * 8 + wd * 2;
      W1F[g] = pk2(W1[k0 * 256 + n], W1[(k0 + 1) * 256 + n]);
    }
    {
      int e = g >> 2, wd = g & 3;
      int lane = e & 63, nt = (e >> 6) & 7, ks2 = (e >> 9) & 1, c = (e >> 10) & 3;
      int q = lane >> 4, lo = lane & 15;
      int n2 = nt * 16 + lo;
      int k20 = c * 64 + (ks2 * 4 + q) * 8 + wd * 2;
      W2F[g] = pk2(W2[k20 * 128 + n2], W2[(k20 + 1) * 128 + n2]);
    }
    if (g < 768) {
      int combo = g >> 6, l = g & 63, c0 = l * 2;
      int a0 = combo / 3, a1 = combo - a0 * 3;
      tblC[g] = pk2(bt[a0 * 128 + c0] + bd[a1 * 128 + c0],
                    bt[a0 * 128 + c0 + 1] + bd[a1 * 128 + c0 + 1]);
    }
  } else {
    const float* elem = cflt;
    const float* chir = cflt + 15104;
    int b = blockIdx.x - wtBlocks;
    int wv = (int)(threadIdx.x >> 6);
    int lane = threadIdx.x & 63;
    int node = b * 4 + wv;
    if (node >= N) return;
    int x0 = x[node * 2], x1 = x[node * 2 + 1];
    int c0 = lane * 2;
    float vx = elem[x0 * 128 + c0] + chir[x1 * 128 + c0];
    float vy = elem[x0 * 128 + c0 + 1] + chir[x1 * 128 + c0 + 1];
    hb[(size_t)node * 64 + lane] = pk2(vx, vy);
  }
}

// ---------------- gather/aggregate: 4 nodes per wave (16 lanes x 16B each) ----------
__global__ __launch_bounds__(256) void k_agg(
    const u32* __restrict__ hb, const int* __restrict__ row_start,
    const int* __restrict__ packed, const u32* __restrict__ tblC,
    u32* __restrict__ z, int N) {
  __shared__ u32 tbl[768];  // [combo][64 u32] == [combo][16 uint4]
  for (int idx = threadIdx.x; idx < 768; idx += 256) tbl[idx] = tblC[idx];
  __syncthreads();
  const uint4* tbl4 = (const uint4*)tbl;
  const int tid = threadIdx.x;
  const int w = tid >> 6, lane = tid & 63;
  const int sub = lane >> 4, li = lane & 15;
  const int node = blockIdx.x * 16 + w * 4 + sub;
  if (node >= N) return;
  const uint4* hb4 = (const uint4*)hb;  // 16 uint4 per row
  uint4 sv = hb4[(size_t)node * 16 + li];
  float2 s0 = up2(sv.x), s1 = up2(sv.y), s2 = up2(sv.z), s3 = up2(sv.w);
  float ax0 = s0.x, ay0 = s0.y, ax1 = s1.x, ay1 = s1.y;
  float ax2 = s2.x, ay2 = s2.y, ax3 = s3.x, ay3 = s3.y;
  const int s_ = row_start[node], e_ = row_start[node + 1];
  int p = s_;
  for (; p + 4 <= e_; p += 4) {
    int k0 = packed[p], k1 = packed[p + 1], k2 = packed[p + 2], k3 = packed[p + 3];
    uint4 r0 = hb4[(size_t)(k0 & 0xFFFFF) * 16 + li];
    uint4 r1 = hb4[(size_t)(k1 & 0xFFFFF) * 16 + li];
    uint4 r2 = hb4[(size_t)(k2 & 0xFFFFF) * 16 + li];
    uint4 r3 = hb4[(size_t)(k3 & 0xFFFFF) * 16 + li];
    uint4 t0 = tbl4[(k0 >> 20) * 16 + li];
    uint4 t1 = tbl4[(k1 >> 20) * 16 + li];
    uint4 t2 = tbl4[(k2 >> 20) * 16 + li];
    uint4 t3 = tbl4[(k3 >> 20) * 16 + li];
    h2 m;
    m = relu2(asH2(r0.x) + asH2(t0.x)); ax0 += (float)m.x; ay0 += (float)m.y;
    m = relu2(asH2(r0.y) + asH2(t0.y)); ax1 += (float)m.x; ay1 += (float)m.y;
    m = relu2(asH2(r0.z) + asH2(t0.z)); ax2 += (float)m.x; ay2 += (float)m.y;
    m = relu2(asH2(r0.w) + asH2(t0.w)); ax3 += (float)m.x; ay3 += (float)m.y;
    m = relu2(asH2(r1.x) + asH2(t1.x)); ax0 += (float)m.x; ay0 += (float)m.y;
    m = relu2(asH2(r1.y) + asH2(t1.y)); ax1 += (float)m.x; ay1 += (float)m.y;
    m = relu2(asH2(r1.z) + asH2(t1.z)); ax2 += (float)m.x; ay2 += (float)m.y;
    m = relu2(asH2(r1.w) + asH2(t1.w)); ax3 += (float)m.x; ay3 += (float)m.y;
    m = relu2(asH2(r2.x) + asH2(t2.x)); ax0 += (float)m.x; ay0 += (float)m.y;
    m = relu2(asH2(r2.y) + asH2(t2.y)); ax1 += (float)m.x; ay1 += (float)m.y;
    m = relu2(asH2(r2.z) + asH2(t2.z)); ax2 += (float)m.x; ay2 += (float)m.y;
    m = relu2(asH2(r2.w) + asH2(t2.w)); ax3 += (float)m.x; ay3 += (float)m.y;
    m = relu2(asH2(r3.x) + asH2(t3.x)); ax0 += (float)m.x; ay0 += (float)m.y;
    m = relu2(asH2(r3.y) + asH2(t3.y)); ax1 += (float)m.x; ay1 += (float)m.y;
    m = relu2(asH2(r3.z) + asH2(t3.z)); ax2 += (float)m.x; ay2 += (float)m.y;
    m = relu2(asH2(r3.w) + asH2(t3.w)); ax3 += (float)m.x; ay3 += (float)m.y;
  }
  for (; p < e_; ++p) {
    int k0 = packed[p];
    uint4 r0 = hb4[(size_t)(k0 & 0xFFFFF) * 16 + li];
    uint4 t0 = tbl4[(k0 >> 20) * 16 + li];
    h2 m;
    m = relu2(asH2(r0.x) + asH2(t0.x)); ax0 += (float)m.x; ay0 += (float)m.y;
    m = relu2(asH2(r0.y) + asH2(t0.y)); ax1 += (float)m.x; ay1 += (float)m.y;
    m = relu2(asH2(r0.z) + asH2(t0.z)); ax2 += (float)m.x; ay2 += (float)m.y;
    m = relu2(asH2(r0.w) + asH2(t0.w)); ax3 += (float)m.x; ay3 += (float)m.y;
  }
  uint4 o;
  o.x = pk2(ax0, ay0); o.y = pk2(ax1, ay1); o.z = pk2(ax2, ay2); o.w = pk2(ax3, ay3);
  ((uint4*)z)[(size_t)node * 16 + li] = o;
}

// ---------------- persistent MLP: weights LDS-resident, one block per CU ----------------
// Stats: per-block partials (plain stores) instead of 65536 same-address global atomics.
__global__ __launch_bounds__(512, 2) void k_mlp(
    const u16* __restrict__ z, const u32* __restrict__ W1F, const u32* __restrict__ W2F,
    const float* __restrict__ b1, const float* __restrict__ b2,
    u16* __restrict__ act, float* __restrict__ statsP, int N, int nTiles) {
  __shared__ u32 sW1[16384];     // 64 KB fragment-ordered W1
  __shared__ u32 sW2[16384];     // 64 KB fragment-ordered W2
  __shared__ u16 sYp[8][1024];   // 16 KB: per-wave private Y (16x64, swizzled)
  __shared__ float sStats[256];  // 1 KB

  const int tid = threadIdx.x;
  const int w = tid >> 6, lane = tid & 63;
  const int lo = lane & 15, q = lane >> 4;

  if (tid < 256) sStats[tid] = 0.f;
  {
    const int4* gW1 = (const int4*)W1F;
    const int4* gW2 = (const int4*)W2F;
    int4* lW1 = (int4*)sW1;
    int4* lW2 = (int4*)sW2;
#pragma unroll
    for (int it = 0; it < 8; ++it) {
      int o = it * 512 + tid;
      lW1[o] = gW1[o];
      lW2[o] = gW2[o];
    }
  }
  __syncthreads();

  float rb1[16], rb2[8];
#pragma unroll
  for (int c = 0; c < 4; ++c)
#pragma unroll
    for (int nt = 0; nt < 4; ++nt)
      rb1[c * 4 + nt] = b1[c * 64 + nt * 16 + lo];
#pragma unroll
  for (int nt = 0; nt < 8; ++nt)
    rb2[nt] = b2[nt * 16 + lo];

  float aSum[8] = {}, aSq[8] = {};
  u16* myY = sYp[w];

  for (int t = blockIdx.x * 8 + w; t < nTiles; t += 2048) {
    const int row0 = t * 16;
    f16x8 a1[4];
    const char* zrow = (const char*)z + (size_t)(row0 + lo) * 256;
#pragma unroll
    for (int ks = 0; ks < 4; ++ks)
      a1[ks] = *(const f16x8*)(zrow + (ks * 4 + q) * 16);

    f32x4 accO[8] = {};
#pragma unroll
    for (int c = 0; c < 4; ++c) {
      f16x8 B1[16];
#pragma unroll
      for (int i = 0; i < 16; ++i)
        B1[i] = *(const f16x8*)((const char*)sW1 + ((c * 16 + i) << 10) + lane * 16);
      f32x4 acc1[4] = {};
#pragma unroll
      for (int ks = 0; ks < 4; ++ks)
#pragma unroll
        for (int nt = 0; nt < 4; ++nt)
          acc1[nt] = __builtin_amdgcn_mfma_f32_16x16x32_f16(a1[ks], B1[ks * 4 + nt], acc1[nt], 0, 0, 0);
#pragma unroll
      for (int nt = 0; nt < 4; ++nt) {
        int ycol = nt * 16 + lo;
        float bias = rb1[c * 4 + nt];
#pragma unroll
        for (int i = 0; i < 4; ++i) {
          int m = q * 4 + i;
          float v = fmaxf(acc1[nt][i] + bias, 0.f);
          myY[m * 64 + (((ycol >> 3) ^ (m & 7)) << 3) + (ycol & 7)] = f2h_bits(v);
        }
      }
      f16x8 B2[16];
#pragma unroll
      for (int i = 0; i < 16; ++i)
        B2[i] = *(const f16x8*)((const char*)sW2 + ((c * 16 + i) << 10) + lane * 16);
#pragma unroll
      for (int ks2 = 0; ks2 < 2; ++ks2) {
        int kq2 = ks2 * 4 + q;
        f16x8 a2 = *(const f16x8*)(myY + lo * 64 + ((kq2 ^ (lo & 7)) << 3));
#pragma unroll
        for (int nt = 0; nt < 8; ++nt)
          accO[nt] = __builtin_amdgcn_mfma_f32_16x16x32_f16(a2, B2[ks2 * 8 + nt], accO[nt], 0, 0, 0);
      }
    }
#pragma unroll
    for (int nt = 0; nt < 8; ++nt) {
      int n2 = nt * 16 + lo;
      float bias = rb2[nt];
#pragma unroll
      for (int i = 0; i < 4; ++i) {
        int row = row0 + q * 4 + i;
        float v = accO[nt][i] + bias;
        act[(size_t)row * 128 + n2] = f2h_bits(v);
        if (row < N) { aSum[nt] += v; aSq[nt] += v * v; }
      }
    }
  }

#pragma unroll
  for (int nt = 0; nt < 8; ++nt) {
    float s = aSum[nt], s2 = aSq[nt];
    s += __shfl_xor(s, 16); s += __shfl_xor(s, 32);
    s2 += __shfl_xor(s2, 16); s2 += __shfl_xor(s2, 32);
    if (q == 0) {
      atomicAdd(&sStats[nt * 16 + lo], s);
      atomicAdd(&sStats[128 + nt * 16 + lo], s2);
    }
  }
  __syncthreads();
  if (tid < 256) statsP[blockIdx.x * 256 + tid] = sStats[tid];  // plain coalesced store
}

// ---------------- BN apply + relu (reduces 256-block partials in-block) -------------
__global__ __launch_bounds__(256) void k_bnapply(
    const u32* __restrict__ act, const float* __restrict__ statsP,
    const float* __restrict__ gamma, const float* __restrict__ beta,
    float invN, u32* __restrict__ hb, int N) {
  __shared__ float sTot[256];
  __shared__ float ssc[128], ssh[128];
  int tid = threadIdx.x;
  {
    float acc = 0.f;
#pragma unroll 8
    for (int b = 0; b < 256; ++b) acc += statsP[b * 256 + tid];  // coalesced across tid
    sTot[tid] = acc;
  }
  __syncthreads();
  if (tid < 128) {
    float mean = sTot[tid] * invN;
    float var = sTot[128 + tid] * invN - mean * mean;
    float inv = rsqrtf(var + 1e-5f);
    float scv = gamma[tid] * inv;
    ssc[tid] = scv;
    ssh[tid] = beta[tid] - mean * scv;
  }
  __syncthreads();
  int total = N * 64;
  for (int i = blockIdx.x * 256 + tid; i < total; i += gridDim.x * 256) {
    int c0 = (i & 63) * 2;
    float2 v = up2(act[i]);
    float ox = fmaxf(v.x * ssc[c0] + ssh[c0], 0.f);
    float oy = fmaxf(v.y * ssc[c0 + 1] + ssh[c0 + 1], 0.f);
    hb[i] = pk2(ox, oy);
  }
}

// ---------------- final: BN (no relu) -> output dtype -------------------------------
__global__ __launch_bounds__(256) void k_final(
    const u32* __restrict__ act, const float* __restrict__ statsP,
    const float* __restrict__ gamma, const float* __restrict__ beta,
    float invN, const int* __restrict__ dflags, void* __restrict__ outv, int N) {
  __shared__ float sTot[256];
  __shared__ float ssc[128], ssh[128];
  int tid = threadIdx.x;
  {
    float acc = 0.f;
#pragma unroll 8
    for (int b = 0; b < 256; ++b) acc += statsP[b * 256 + tid];
    sTot[tid] = acc;
  }
  __syncthreads();
  if (tid < 128) {
    float mean = sTot[tid] * invN;
    float var = sTot[128 + tid] * invN - mean * mean;
    float inv = rsqrtf(var + 1e-5f);
    float scv = gamma[tid] * inv;
    ssc[tid] = scv;
    ssh[tid] = beta[tid] - mean * scv;
  }
  __syncthreads();
  int isbf = dflags[0];
  int total = N * 64;
  for (int i = blockIdx.x * 256 + tid; i < total; i += gridDim.x * 256) {
    int c0 = (i & 63) * 2;
    float2 v = up2(act[i]);
    float ox = v.x * ssc[c0] + ssh[c0];
    float oy = v.y * ssc[c0 + 1] + ssh[c0 + 1];
    if (isbf) ((u32*)outv)[i] = (u32)f2bf(ox) | ((u32)f2bf(oy) << 16);
    else { float2 o; o.x = ox; o.y = oy; ((float2*)outv)[i] = o; }
  }
}

extern "C" void kernel_launch(void* const* d_in, const int* in_sizes, int n_in,
                              void* d_out, int out_size, void* d_ws, size_t ws_size,
                              hipStream_t stream) {
  const int* xR  = (const int*)d_in[0];
  const int* eiR = (const int*)d_in[1];
  const int* eaR = (const int*)d_in[2];
  const u16* emR = (const u16*)d_in[3];
  const u16* chR = (const u16*)d_in[4];
  const u16* btR = (const u16*)d_in[5];
  const u16* bdR = (const u16*)d_in[6];
  const u16* W1R = (const u16*)d_in[7];
  const u16* b1R = (const u16*)d_in[8];
  const u16* W2R = (const u16*)d_in[9];
  const u16* b2R = (const u16*)d_in[10];
  const u16* gR  = (const u16*)d_in[11];
  const u16* beR = (const u16*)d_in[12];

  const int N = in_sizes[0] / 2;      // 50000
  const int E = in_sizes[1] / 2;      // 600000
  const int L = in_sizes[11] / 128;   // 5
  const int Mpad = ((N + 63) / 64) * 64;
  const int nCh = (N + 1023) / 1024;
  const int NPad = nCh * 1024;
  const int nTiles = (N + 15) / 16;   // 3125

  char* base = (char*)d_ws;
  size_t off = 0;
  auto take = [&](size_t bytes) -> void* {
    void* p = base + off;
    off += (bytes + 255) & ~(size_t)255;
    return p;
  };
  int*   dflags    = (int*)  take(256);
  int*   x32       = (int*)  take((size_t)2 * N * 4);
  int*   ei32      = (int*)  take((size_t)2 * E * 4);
  int*   combo     = (int*)  take((size_t)E * 4);
  float* cflt      = (float*)take(83712 * 4);
  u32*   act       = (u32*)  take((size_t)Mpad * 64 * 4);   // raw MLP out (f16 pairs)
  u32*   hb        = (u32*)  take((size_t)Mpad * 64 * 4);   // BN-applied relu'd h
  u16*   zb        = (u16*)  take((size_t)Mpad * 128 * 2);
  int*   packed    = (int*)  take((size_t)E * 4);
  int*   row_start = (int*)  take((size_t)(N + 1) * 4);
  int*   cursor    = (int*)  take((size_t)N * 4);
  int*   counts    = (int*)  take((size_t)NPad * 4);
  int*   bsum      = (int*)  take(64 * 4);
  int*   boff      = (int*)  take(64 * 4);
  float* statsP    = (float*)take((size_t)256 * 256 * 4);   // per-block partials (reused per layer)
  u32*   W1F       = (u32*)  take(16384 * 4);
  u32*   W2F       = (u32*)  take(16384 * 4);
  u32*   tblC      = (u32*)  take(768 * 4);
  const size_t need = off;
  (void)n_in;

  float* cB1 = cflt + 49280;
  float* cB2 = cflt + 82304;
  float* cGamma = cflt + 82432;
  float* cBeta = cflt + 83072;

  if (need > ws_size) {
    k_detect<<<dim3(1), dim3(256), 0, stream>>>(emR, eiR, dflags);
    k_canary<<<dim3((out_size + 255) / 256), dim3(256), 0, stream>>>(
        (u32*)d_out, dflags, out_size, 0x40004000u, 0x40000000u);
    return;
  }

  // merged detect + zero(counts)
  const int nzBlocks = (NPad + 255) / 256;
  k_init<<<dim3(nzBlocks + 1), dim3(256), 0, stream>>>(emR, eiR, dflags, counts, NPad);

  const int nPairs = N + 2 * E;
  const int intBlocks = (nPairs + 255) / 256;
  const int fltBlocks = (83712 + 255) / 256;
  k_cvt<<<dim3(intBlocks + fltBlocks), dim3(256), 0, stream>>>(
      xR, eiR, eaR, emR, chR, btR, bdR, W1R, b1R, W2R, b2R, gR, beR,
      dflags, x32, ei32, combo, counts, cflt, N, E, intBlocks);

  k_chunksum<<<dim3(nCh), dim3(256), 0, stream>>>(counts, bsum);
  k_chunkscan<<<dim3(1), dim3(64), 0, stream>>>(bsum, boff, row_start, N, nCh);
  k_scanapply<<<dim3(nCh), dim3(256), 0, stream>>>(counts, boff, row_start, cursor, N);
  k_scatter<<<dim3((E + 255) / 256), dim3(256), 0, stream>>>(ei32, combo, cursor, packed, E);

  const int wtBlocks = 64;  // 16384 threads for W1F/W2F words
  k_prep<<<dim3(wtBlocks + (N + 3) / 4), dim3(256), 0, stream>>>(
      cflt, x32, W1F, W2F, tblC, hb, N, wtBlocks);

  const float invN = 1.0f / (float)N;
  for (int l = 0; l < L; ++l) {
    k_agg<<<dim3((N + 15) / 16), dim3(256), 0, stream>>>(
        hb, row_start, packed, tblC, (u32*)zb, N);
    k_mlp<<<dim3(256), dim3(512), 0, stream>>>(
        zb, W1F, W2F, cB1, cB2, (u16*)act, statsP, N, nTiles);
    if (l < L - 1) {
      k_bnapply<<<dim3(256), dim3(256), 0, stream>>>(
          act, statsP, cGamma + (size_t)l * 128, cBeta + (size_t)l * 128,
          invN, hb, N);
    }
  }
  k_final<<<dim3(256), dim3(256), 0, stream>>>(
      act, statsP, cGamma + (size_t)(L - 1) * 128,
      cBeta + (size_t)(L - 1) * 128, invN, dflags, d_out, N);
}

// Round 4
// 449.464 us; speedup vs baseline: 1.2647x; 1.2239x over previous
//
#include <hip/hip_runtime.h>

typedef _Float16 f16;
typedef _Float16 f16x8 __attribute__((ext_vector_type(8)));
typedef _Float16 h2 __attribute__((ext_vector_type(2)));
typedef float f32x4 __attribute__((ext_vector_type(4)));
typedef unsigned short u16;
typedef unsigned int u32;

// ---------- conversions ----------
__device__ __forceinline__ float bf2f(u16 b) {
  union { u32 u; float f; } t; t.u = ((u32)b) << 16; return t.f;
}
__device__ __forceinline__ u16 f2bf(float f) {  // RNE float->bf16 bits
  union { float f; u32 u; } t; t.f = f;
  u32 u = t.u;
  return (u16)((u + 0x7FFFu + ((u >> 16) & 1u)) >> 16);
}
__device__ __forceinline__ u16 f2h_bits(float f) {
  f16 h = (f16)f;
  union { f16 h; u16 u; } t; t.h = h; return t.u;
}
__device__ __forceinline__ float2 up2(u32 p) {  // f16 pair -> float2
  union { u32 u; f16 h[2]; } t; t.u = p;
  float2 r; r.x = (float)t.h[0]; r.y = (float)t.h[1]; return r;
}
__device__ __forceinline__ u32 pk2(float x, float y) {  // float2 -> f16 pair
  return (u32)f2h_bits(x) | ((u32)f2h_bits(y) << 16);
}
__device__ __forceinline__ h2 asH2(u32 u) {
  union { u32 u; h2 h; } t; t.u = u; return t.h;
}
__device__ __forceinline__ h2 relu2(h2 a) {
#if __has_builtin(__builtin_elementwise_max)
  h2 z = {(_Float16)0, (_Float16)0};
  return __builtin_elementwise_max(a, z);
#else
  h2 r;
  r.x = a.x > (_Float16)0 ? a.x : (_Float16)0;
  r.y = a.y > (_Float16)0 ? a.y : (_Float16)0;
  return r;
#endif
}

// ---------------- dtype detection (standalone, canary path only) ----------------
__global__ void k_detect(const u16* __restrict__ elemRaw, const int* __restrict__ eiRaw,
                         int* __restrict__ dflags) {
  __shared__ int bad, nzOdd;
  if (threadIdx.x == 0) { bad = 0; nzOdd = 0; }
  __syncthreads();
  int myBad = 0;
  for (int i = threadIdx.x; i < 4096; i += 256) {
    float v = bf2f(elemRaw[i]);
    if (!(v > -0.2f && v < 0.2f)) myBad++;
  }
  if (myBad) atomicAdd(&bad, myBad);
  int myNz = 0;
  for (int i = threadIdx.x; i < 1024; i += 256)
    if (eiRaw[2 * i + 1] != 0) myNz++;  // int64 high words would be 0
  if (myNz) atomicAdd(&nzOdd, myNz);
  __syncthreads();
  if (threadIdx.x == 0) {
    dflags[0] = (bad == 0) ? 1 : 0;
    dflags[1] = (nzOdd > 16) ? 1 : 0;
  }
}

// ---------------- merged detect + zero (counts + statsC copies) ----------------
__global__ void k_init(const u16* __restrict__ elemRaw, const int* __restrict__ eiRaw,
                       int* __restrict__ dflags, int* __restrict__ counts,
                       float* __restrict__ statsC, int NPad, int statsZ) {
  if (blockIdx.x == 0) {
    __shared__ int bad, nzOdd;
    if (threadIdx.x == 0) { bad = 0; nzOdd = 0; }
    __syncthreads();
    int myBad = 0;
    for (int i = threadIdx.x; i < 4096; i += 256) {
      float v = bf2f(elemRaw[i]);
      if (!(v > -0.2f && v < 0.2f)) myBad++;
    }
    if (myBad) atomicAdd(&bad, myBad);
    int myNz = 0;
    for (int i = threadIdx.x; i < 1024; i += 256)
      if (eiRaw[2 * i + 1] != 0) myNz++;
    if (myNz) atomicAdd(&nzOdd, myNz);
    __syncthreads();
    if (threadIdx.x == 0) {
      dflags[0] = (bad == 0) ? 1 : 0;
      dflags[1] = (nzOdd > 16) ? 1 : 0;
    }
  } else {
    int i = (blockIdx.x - 1) * 256 + threadIdx.x;
    if (i < NPad) counts[i] = 0;
    else if (i < NPad + statsZ) statsC[i - NPad] = 0.f;
  }
}

__global__ void k_canary(u32* __restrict__ out, const int* __restrict__ dflags,
                         int out_size, u32 pBf, u32 pF32) {
  int isbf = dflags[0];
  int words = isbf ? (out_size >> 1) : out_size;
  int i = blockIdx.x * 256 + threadIdx.x;
  if (i < words) out[i] = isbf ? pBf : pF32;
}

// ---------------- combined canonicalize (+fused dst histogram) ----------------
__global__ void k_cvt(const int* __restrict__ xR, const int* __restrict__ eiR,
                      const int* __restrict__ eaR,
                      const u16* e0, const u16* e1, const u16* e2, const u16* e3,
                      const u16* e4, const u16* e5, const u16* e6, const u16* e7,
                      const u16* e8, const u16* e9,
                      const int* __restrict__ dflags,
                      int* __restrict__ x32, int* __restrict__ ei32, int* __restrict__ combo,
                      int* __restrict__ counts, float* __restrict__ dst,
                      int N, int E, int intBlocks) {
  if ((int)blockIdx.x < intBlocks) {
    int pi = blockIdx.x * 256 + threadIdx.x;
    int nPairs = N + 2 * E;
    if (pi >= nPairs) return;
    int is32 = dflags[1];
    const int* src; int local; int kind;
    if (pi < N) { src = xR; local = pi; kind = 0; }
    else if (pi < N + E) { src = eiR; local = pi - N; kind = 1; }
    else { src = eaR; local = pi - N - E; kind = 2; }
    int j0 = 2 * local;
    int v0, v1;
    if (is32) { int2 v = *(const int2*)(src + j0); v0 = v.x; v1 = v.y; }
    else      { int4 v = *(const int4*)(src + 2 * j0); v0 = v.x; v1 = v.z; }
    if (kind == 0) { x32[j0] = v0; x32[j0 + 1] = v1; }
    else if (kind == 1) {
      ei32[j0] = v0; ei32[j0 + 1] = v1;
      if (j0 >= E) {  // dst half
        atomicAdd(&counts[v0], 1);
        atomicAdd(&counts[v1], 1);
      }
    } else {
      combo[local] = v0 * 3 + v1;
    }
  } else {
    int i = (blockIdx.x - intBlocks) * 256 + threadIdx.x;
    if (i >= 83712) return;
    int isbf = dflags[0];
    const u16* src; int j;
    if      (i < 15104) { src = e0; j = i; }
    else if (i < 15616) { src = e1; j = i - 15104; }
    else if (i < 16128) { src = e2; j = i - 15616; }
    else if (i < 16512) { src = e3; j = i - 16128; }
    else if (i < 49280) { src = e4; j = i - 16512; }
    else if (i < 49536) { src = e5; j = i - 49280; }
    else if (i < 82304) { src = e6; j = i - 49536; }
    else if (i < 82432) { src = e7; j = i - 82304; }
    else if (i < 83072) { src = e8; j = i - 82432; }
    else                { src = e9; j = i - 83072; }
    dst[i] = isbf ? bf2f(src[j]) : ((const float*)src)[j];
  }
}

// ---------------- CSR scan ----------------
__global__ void k_chunksum(const int* __restrict__ counts, int* __restrict__ bsum) {
  int tid = threadIdx.x, lane = tid & 63, w = tid >> 6;
  const int4* c4 = (const int4*)(counts + blockIdx.x * 1024);
  int4 v = c4[tid];
  int s = v.x + v.y + v.z + v.w;
#pragma unroll
  for (int d = 1; d < 64; d <<= 1) s += __shfl_xor(s, d);
  __shared__ int ws[4];
  if (lane == 0) ws[w] = s;
  __syncthreads();
  if (tid == 0) bsum[blockIdx.x] = ws[0] + ws[1] + ws[2] + ws[3];
}

__global__ void k_chunkscan(const int* __restrict__ bsum, int* __restrict__ boff,
                            int* __restrict__ row_start, int N, int nCh) {
  int t = threadIdx.x;
  int v = (t < nCh) ? bsum[t] : 0;
  int incl = v;
#pragma unroll
  for (int d = 1; d < 64; d <<= 1) { int tmp = __shfl_up(incl, d); if (t >= d) incl += tmp; }
  boff[t] = incl - v;
  if (t == 63) row_start[N] = incl;  // = E
}

__global__ void k_scanapply(const int* __restrict__ counts, const int* __restrict__ boff,
                            int* __restrict__ row_start, int* __restrict__ cursor, int N) {
  int tid = threadIdx.x, lane = tid & 63, w = tid >> 6;
  int base = blockIdx.x * 1024 + tid * 4;
  int4 v = *(const int4*)(counts + base);
  int tsum = v.x + v.y + v.z + v.w;
  int incl = tsum;
#pragma unroll
  for (int d = 1; d < 64; d <<= 1) { int tmp = __shfl_up(incl, d); if (lane >= d) incl += tmp; }
  __shared__ int ws[4];
  if (lane == 63) ws[w] = incl;
  __syncthreads();
  int woff = 0;
  for (int j = 0; j < w; ++j) woff += ws[j];
  int excl = boff[blockIdx.x] + woff + incl - tsum;
  int e0 = excl, e1 = excl + v.x, e2 = e1 + v.y, e3 = e2 + v.z;
  if (base < N)     { row_start[base] = e0;     cursor[base] = e0; }
  if (base + 1 < N) { row_start[base + 1] = e1; cursor[base + 1] = e1; }
  if (base + 2 < N) { row_start[base + 2] = e2; cursor[base + 2] = e2; }
  if (base + 3 < N) { row_start[base + 3] = e3; cursor[base + 3] = e3; }
}

__global__ void k_scatter(const int* __restrict__ ei, const int* __restrict__ combo,
                          int* cursor, int* packed, int E) {
  int e = blockIdx.x * blockDim.x + threadIdx.x;
  if (e >= E) return;
  int s = ei[e], d = ei[E + e];
  int cb = combo[e];
  int pos = atomicAdd(&cursor[d], 1);
  packed[pos] = s | (cb << 20);  // src < 2^20, combo in [0,12)
}

// ---------------- fragment-ordered weights + bond table + h0 (merged) ----------------
__global__ void k_prep(const float* __restrict__ cflt, const int* __restrict__ x,
                       u32* __restrict__ W1F, u32* __restrict__ W2F,
                       u32* __restrict__ tblC, u32* __restrict__ hb, int N, int wtBlocks) {
  if ((int)blockIdx.x < wtBlocks) {
    const float* W1 = cflt + 16512;   // [128][256] row-major (k, n)
    const float* W2 = cflt + 49536;   // [256][128] row-major (k2, n2)
    const float* bt = cflt + 15616;
    const float* bd = cflt + 16128;
    int g = blockIdx.x * 256 + threadIdx.x;  // 0..16383 (one u32 of each table)
    {
      int e = g >> 2, wd = g & 3;
      int lane = e & 63, nt = (e >> 6) & 3, ks = (e >> 8) & 3, c = (e >> 10) & 3;
      int q = lane >> 4, lo = lane & 15;
      int n = c * 64 + nt * 16 + lo;
      int k0 = (ks * 4 + q) * 8 + wd * 2;
      W1F[g] = pk2(W1[k0 * 256 + n], W1[(k0 + 1) * 256 + n]);
    }
    {
      int e = g >> 2, wd = g & 3;
      int lane = e & 63, nt = (e >> 6) & 7, ks2 = (e >> 9) & 1, c = (e >> 10) & 3;
      int q = lane >> 4, lo = lane & 15;
      int n2 = nt * 16 + lo;
      int k20 = c * 64 + (ks2 * 4 + q) * 8 + wd * 2;
      W2F[g] = pk2(W2[k20 * 128 + n2], W2[(k20 + 1) * 128 + n2]);
    }
    if (g < 768) {
      int combo = g >> 6, l = g & 63, c0 = l * 2;
      int a0 = combo / 3, a1 = combo - a0 * 3;
      tblC[g] = pk2(bt[a0 * 128 + c0] + bd[a1 * 128 + c0],
                    bt[a0 * 128 + c0 + 1] + bd[a1 * 128 + c0 + 1]);
    }
  } else {
    const float* elem = cflt;
    const float* chir = cflt + 15104;
    int b = blockIdx.x - wtBlocks;
    int wv = (int)(threadIdx.x >> 6);
    int lane = threadIdx.x & 63;
    int node = b * 4 + wv;
    if (node >= N) return;
    int x0 = x[node * 2], x1 = x[node * 2 + 1];
    int c0 = lane * 2;
    float vx = elem[x0 * 128 + c0] + chir[x1 * 128 + c0];
    float vy = elem[x0 * 128 + c0 + 1] + chir[x1 * 128 + c0 + 1];
    hb[(size_t)node * 64 + lane] = pk2(vx, vy);
  }
}

// ---------------- gather/aggregate: 4 nodes per wave (16 lanes x 16B each) ----------
__global__ __launch_bounds__(256) void k_agg(
    const u32* __restrict__ hb, const int* __restrict__ row_start,
    const int* __restrict__ packed, const u32* __restrict__ tblC,
    u32* __restrict__ z, int N) {
  __shared__ u32 tbl[768];  // [combo][64 u32] == [combo][16 uint4]
  for (int idx = threadIdx.x; idx < 768; idx += 256) tbl[idx] = tblC[idx];
  __syncthreads();
  const uint4* tbl4 = (const uint4*)tbl;
  const int tid = threadIdx.x;
  const int w = tid >> 6, lane = tid & 63;
  const int sub = lane >> 4, li = lane & 15;
  const int node = blockIdx.x * 16 + w * 4 + sub;
  if (node >= N) return;
  const uint4* hb4 = (const uint4*)hb;  // 16 uint4 per row
  uint4 sv = hb4[(size_t)node * 16 + li];
  float2 s0 = up2(sv.x), s1 = up2(sv.y), s2 = up2(sv.z), s3 = up2(sv.w);
  float ax0 = s0.x, ay0 = s0.y, ax1 = s1.x, ay1 = s1.y;
  float ax2 = s2.x, ay2 = s2.y, ax3 = s3.x, ay3 = s3.y;
  const int s_ = row_start[node], e_ = row_start[node + 1];
  int p = s_;
  for (; p + 4 <= e_; p += 4) {
    int k0 = packed[p], k1 = packed[p + 1], k2 = packed[p + 2], k3 = packed[p + 3];
    uint4 r0 = hb4[(size_t)(k0 & 0xFFFFF) * 16 + li];
    uint4 r1 = hb4[(size_t)(k1 & 0xFFFFF) * 16 + li];
    uint4 r2 = hb4[(size_t)(k2 & 0xFFFFF) * 16 + li];
    uint4 r3 = hb4[(size_t)(k3 & 0xFFFFF) * 16 + li];
    uint4 t0 = tbl4[(k0 >> 20) * 16 + li];
    uint4 t1 = tbl4[(k1 >> 20) * 16 + li];
    uint4 t2 = tbl4[(k2 >> 20) * 16 + li];
    uint4 t3 = tbl4[(k3 >> 20) * 16 + li];
    h2 m;
    m = relu2(asH2(r0.x) + asH2(t0.x)); ax0 += (float)m.x; ay0 += (float)m.y;
    m = relu2(asH2(r0.y) + asH2(t0.y)); ax1 += (float)m.x; ay1 += (float)m.y;
    m = relu2(asH2(r0.z) + asH2(t0.z)); ax2 += (float)m.x; ay2 += (float)m.y;
    m = relu2(asH2(r0.w) + asH2(t0.w)); ax3 += (float)m.x; ay3 += (float)m.y;
    m = relu2(asH2(r1.x) + asH2(t1.x)); ax0 += (float)m.x; ay0 += (float)m.y;
    m = relu2(asH2(r1.y) + asH2(t1.y)); ax1 += (float)m.x; ay1 += (float)m.y;
    m = relu2(asH2(r1.z) + asH2(t1.z)); ax2 += (float)m.x; ay2 += (float)m.y;
    m = relu2(asH2(r1.w) + asH2(t1.w)); ax3 += (float)m.x; ay3 += (float)m.y;
    m = relu2(asH2(r2.x) + asH2(t2.x)); ax0 += (float)m.x; ay0 += (float)m.y;
    m = relu2(asH2(r2.y) + asH2(t2.y)); ax1 += (float)m.x; ay1 += (float)m.y;
    m = relu2(asH2(r2.z) + asH2(t2.z)); ax2 += (float)m.x; ay2 += (float)m.y;
    m = relu2(asH2(r2.w) + asH2(t2.w)); ax3 += (float)m.x; ay3 += (float)m.y;
    m = relu2(asH2(r3.x) + asH2(t3.x)); ax0 += (float)m.x; ay0 += (float)m.y;
    m = relu2(asH2(r3.y) + asH2(t3.y)); ax1 += (float)m.x; ay1 += (float)m.y;
    m = relu2(asH2(r3.z) + asH2(t3.z)); ax2 += (float)m.x; ay2 += (float)m.y;
    m = relu2(asH2(r3.w) + asH2(t3.w)); ax3 += (float)m.x; ay3 += (float)m.y;
  }
  for (; p < e_; ++p) {
    int k0 = packed[p];
    uint4 r0 = hb4[(size_t)(k0 & 0xFFFFF) * 16 + li];
    uint4 t0 = tbl4[(k0 >> 20) * 16 + li];
    h2 m;
    m = relu2(asH2(r0.x) + asH2(t0.x)); ax0 += (float)m.x; ay0 += (float)m.y;
    m = relu2(asH2(r0.y) + asH2(t0.y)); ax1 += (float)m.x; ay1 += (float)m.y;
    m = relu2(asH2(r0.z) + asH2(t0.z)); ax2 += (float)m.x; ay2 += (float)m.y;
    m = relu2(asH2(r0.w) + asH2(t0.w)); ax3 += (float)m.x; ay3 += (float)m.y;
  }
  uint4 o;
  o.x = pk2(ax0, ay0); o.y = pk2(ax1, ay1); o.z = pk2(ax2, ay2); o.w = pk2(ax3, ay3);
  ((uint4*)z)[(size_t)node * 16 + li] = o;
}

// ---------------- persistent MLP: weights LDS-resident, one block per CU ----------------
// Stats: atomicAdd into 32 copies (block b -> copy b&31): 8-way contention per address
// instead of 256-way (the R0 atomic storm that left the kernel idle-draining ~30us).
__global__ __launch_bounds__(512, 2) void k_mlp(
    const u16* __restrict__ z, const u32* __restrict__ W1F, const u32* __restrict__ W2F,
    const float* __restrict__ b1, const float* __restrict__ b2,
    u16* __restrict__ act, float* __restrict__ statsC, int N, int nTiles) {
  __shared__ u32 sW1[16384];     // 64 KB fragment-ordered W1
  __shared__ u32 sW2[16384];     // 64 KB fragment-ordered W2
  __shared__ u16 sYp[8][1024];   // 16 KB: per-wave private Y (16x64, swizzled)
  __shared__ float sStats[256];  // 1 KB

  const int tid = threadIdx.x;
  const int w = tid >> 6, lane = tid & 63;
  const int lo = lane & 15, q = lane >> 4;

  if (tid < 256) sStats[tid] = 0.f;
  {
    const int4* gW1 = (const int4*)W1F;
    const int4* gW2 = (const int4*)W2F;
    int4* lW1 = (int4*)sW1;
    int4* lW2 = (int4*)sW2;
#pragma unroll
    for (int it = 0; it < 8; ++it) {
      int o = it * 512 + tid;
      lW1[o] = gW1[o];
      lW2[o] = gW2[o];
    }
  }
  __syncthreads();

  float rb1[16], rb2[8];
#pragma unroll
  for (int c = 0; c < 4; ++c)
#pragma unroll
    for (int nt = 0; nt < 4; ++nt)
      rb1[c * 4 + nt] = b1[c * 64 + nt * 16 + lo];
#pragma unroll
  for (int nt = 0; nt < 8; ++nt)
    rb2[nt] = b2[nt * 16 + lo];

  float aSum[8] = {}, aSq[8] = {};
  u16* myY = sYp[w];

  for (int t = blockIdx.x * 8 + w; t < nTiles; t += 2048) {
    const int row0 = t * 16;
    f16x8 a1[4];
    const char* zrow = (const char*)z + (size_t)(row0 + lo) * 256;
#pragma unroll
    for (int ks = 0; ks < 4; ++ks)
      a1[ks] = *(const f16x8*)(zrow + (ks * 4 + q) * 16);

    f32x4 accO[8] = {};
#pragma unroll
    for (int c = 0; c < 4; ++c) {
      f16x8 B1[16];
#pragma unroll
      for (int i = 0; i < 16; ++i)
        B1[i] = *(const f16x8*)((const char*)sW1 + ((c * 16 + i) << 10) + lane * 16);
      f32x4 acc1[4] = {};
#pragma unroll
      for (int ks = 0; ks < 4; ++ks)
#pragma unroll
        for (int nt = 0; nt < 4; ++nt)
          acc1[nt] = __builtin_amdgcn_mfma_f32_16x16x32_f16(a1[ks], B1[ks * 4 + nt], acc1[nt], 0, 0, 0);
#pragma unroll
      for (int nt = 0; nt < 4; ++nt) {
        int ycol = nt * 16 + lo;
        float bias = rb1[c * 4 + nt];
#pragma unroll
        for (int i = 0; i < 4; ++i) {
          int m = q * 4 + i;
          float v = fmaxf(acc1[nt][i] + bias, 0.f);
          myY[m * 64 + (((ycol >> 3) ^ (m & 7)) << 3) + (ycol & 7)] = f2h_bits(v);
        }
      }
      f16x8 B2[16];
#pragma unroll
      for (int i = 0; i < 16; ++i)
        B2[i] = *(const f16x8*)((const char*)sW2 + ((c * 16 + i) << 10) + lane * 16);
#pragma unroll
      for (int ks2 = 0; ks2 < 2; ++ks2) {
        int kq2 = ks2 * 4 + q;
        f16x8 a2 = *(const f16x8*)(myY + lo * 64 + ((kq2 ^ (lo & 7)) << 3));
#pragma unroll
        for (int nt = 0; nt < 8; ++nt)
          accO[nt] = __builtin_amdgcn_mfma_f32_16x16x32_f16(a2, B2[ks2 * 8 + nt], accO[nt], 0, 0, 0);
      }
    }
#pragma unroll
    for (int nt = 0; nt < 8; ++nt) {
      int n2 = nt * 16 + lo;
      float bias = rb2[nt];
#pragma unroll
      for (int i = 0; i < 4; ++i) {
        int row = row0 + q * 4 + i;
        float v = accO[nt][i] + bias;
        act[(size_t)row * 128 + n2] = f2h_bits(v);
        if (row < N) { aSum[nt] += v; aSq[nt] += v * v; }
      }
    }
  }

#pragma unroll
  for (int nt = 0; nt < 8; ++nt) {
    float s = aSum[nt], s2 = aSq[nt];
    s += __shfl_xor(s, 16); s += __shfl_xor(s, 32);
    s2 += __shfl_xor(s2, 16); s2 += __shfl_xor(s2, 32);
    if (q == 0) {
      atomicAdd(&sStats[nt * 16 + lo], s);
      atomicAdd(&sStats[128 + nt * 16 + lo], s2);
    }
  }
  __syncthreads();
  if (tid < 256) atomicAdd(&statsC[(blockIdx.x & 31) * 256 + tid], sStats[tid]);
}

// ---------------- BN apply + relu (sums 32 stat copies in a cheap preamble) ---------
__global__ __launch_bounds__(256) void k_bnapply(
    const u32* __restrict__ act, const float* __restrict__ statsC,
    const float* __restrict__ gamma, const float* __restrict__ beta,
    float invN, u32* __restrict__ hb, int N) {
  __shared__ float sTot[256];
  __shared__ float ssc[128], ssh[128];
  int tid = threadIdx.x;
  {
    float acc = 0.f;
#pragma unroll
    for (int c = 0; c < 32; ++c) acc += statsC[c * 256 + tid];  // 32 KB, L2-hot
    sTot[tid] = acc;
  }
  __syncthreads();
  if (tid < 128) {
    float mean = sTot[tid] * invN;
    float var = sTot[128 + tid] * invN - mean * mean;
    float inv = rsqrtf(var + 1e-5f);
    float scv = gamma[tid] * inv;
    ssc[tid] = scv;
    ssh[tid] = beta[tid] - mean * scv;
  }
  __syncthreads();
  int total = N * 64;
  for (int i = blockIdx.x * 256 + tid; i < total; i += gridDim.x * 256) {
    int c0 = (i & 63) * 2;
    float2 v = up2(act[i]);
    float ox = fmaxf(v.x * ssc[c0] + ssh[c0], 0.f);
    float oy = fmaxf(v.y * ssc[c0 + 1] + ssh[c0 + 1], 0.f);
    hb[i] = pk2(ox, oy);
  }
}

// ---------------- final: BN (no relu) -> output dtype -------------------------------
__global__ __launch_bounds__(256) void k_final(
    const u32* __restrict__ act, const float* __restrict__ statsC,
    const float* __restrict__ gamma, const float* __restrict__ beta,
    float invN, const int* __restrict__ dflags, void* __restrict__ outv, int N) {
  __shared__ float sTot[256];
  __shared__ float ssc[128], ssh[128];
  int tid = threadIdx.x;
  {
    float acc = 0.f;
#pragma unroll
    for (int c = 0; c < 32; ++c) acc += statsC[c * 256 + tid];
    sTot[tid] = acc;
  }
  __syncthreads();
  if (tid < 128) {
    float mean = sTot[tid] * invN;
    float var = sTot[128 + tid] * invN - mean * mean;
    float inv = rsqrtf(var + 1e-5f);
    float scv = gamma[tid] * inv;
    ssc[tid] = scv;
    ssh[tid] = beta[tid] - mean * scv;
  }
  __syncthreads();
  int isbf = dflags[0];
  int total = N * 64;
  for (int i = blockIdx.x * 256 + tid; i < total; i += gridDim.x * 256) {
    int c0 = (i & 63) * 2;
    float2 v = up2(act[i]);
    float ox = v.x * ssc[c0] + ssh[c0];
    float oy = v.y * ssc[c0 + 1] + ssh[c0 + 1];
    if (isbf) ((u32*)outv)[i] = (u32)f2bf(ox) | ((u32)f2bf(oy) << 16);
    else { float2 o; o.x = ox; o.y = oy; ((float2*)outv)[i] = o; }
  }
}

extern "C" void kernel_launch(void* const* d_in, const int* in_sizes, int n_in,
                              void* d_out, int out_size, void* d_ws, size_t ws_size,
                              hipStream_t stream) {
  const int* xR  = (const int*)d_in[0];
  const int* eiR = (const int*)d_in[1];
  const int* eaR = (const int*)d_in[2];
  const u16* emR = (const u16*)d_in[3];
  const u16* chR = (const u16*)d_in[4];
  const u16* btR = (const u16*)d_in[5];
  const u16* bdR = (const u16*)d_in[6];
  const u16* W1R = (const u16*)d_in[7];
  const u16* b1R = (const u16*)d_in[8];
  const u16* W2R = (const u16*)d_in[9];
  const u16* b2R = (const u16*)d_in[10];
  const u16* gR  = (const u16*)d_in[11];
  const u16* beR = (const u16*)d_in[12];

  const int N = in_sizes[0] / 2;      // 50000
  const int E = in_sizes[1] / 2;      // 600000
  const int L = in_sizes[11] / 128;   // 5
  const int Mpad = ((N + 63) / 64) * 64;
  const int nCh = (N + 1023) / 1024;
  const int NPad = nCh * 1024;
  const int nTiles = (N + 15) / 16;   // 3125

  char* base = (char*)d_ws;
  size_t off = 0;
  auto take = [&](size_t bytes) -> void* {
    void* p = base + off;
    off += (bytes + 255) & ~(size_t)255;
    return p;
  };
  int*   dflags    = (int*)  take(256);
  int*   x32       = (int*)  take((size_t)2 * N * 4);
  int*   ei32      = (int*)  take((size_t)2 * E * 4);
  int*   combo     = (int*)  take((size_t)E * 4);
  float* cflt      = (float*)take(83712 * 4);
  u32*   act       = (u32*)  take((size_t)Mpad * 64 * 4);   // raw MLP out (f16 pairs)
  u32*   hb        = (u32*)  take((size_t)Mpad * 64 * 4);   // BN-applied relu'd h
  u16*   zb        = (u16*)  take((size_t)Mpad * 128 * 2);
  int*   packed    = (int*)  take((size_t)E * 4);
  int*   row_start = (int*)  take((size_t)(N + 1) * 4);
  int*   cursor    = (int*)  take((size_t)N * 4);
  int*   counts    = (int*)  take((size_t)NPad * 4);
  int*   bsum      = (int*)  take(64 * 4);
  int*   boff      = (int*)  take(64 * 4);
  float* statsC    = (float*)take((size_t)L * 32 * 256 * 4);  // 32 copies per layer
  u32*   W1F       = (u32*)  take(16384 * 4);
  u32*   W2F       = (u32*)  take(16384 * 4);
  u32*   tblC      = (u32*)  take(768 * 4);
  const size_t need = off;
  (void)n_in;

  float* cB1 = cflt + 49280;
  float* cB2 = cflt + 82304;
  float* cGamma = cflt + 82432;
  float* cBeta = cflt + 83072;

  if (need > ws_size) {
    k_detect<<<dim3(1), dim3(256), 0, stream>>>(emR, eiR, dflags);
    k_canary<<<dim3((out_size + 255) / 256), dim3(256), 0, stream>>>(
        (u32*)d_out, dflags, out_size, 0x40004000u, 0x40000000u);
    return;
  }

  // merged detect + zero(counts, statsC)
  const int statsZ = L * 32 * 256;
  const int nzBlocks = (NPad + statsZ + 255) / 256;
  k_init<<<dim3(nzBlocks + 1), dim3(256), 0, stream>>>(emR, eiR, dflags, counts, statsC,
                                                       NPad, statsZ);

  const int nPairs = N + 2 * E;
  const int intBlocks = (nPairs + 255) / 256;
  const int fltBlocks = (83712 + 255) / 256;
  k_cvt<<<dim3(intBlocks + fltBlocks), dim3(256), 0, stream>>>(
      xR, eiR, eaR, emR, chR, btR, bdR, W1R, b1R, W2R, b2R, gR, beR,
      dflags, x32, ei32, combo, counts, cflt, N, E, intBlocks);

  k_chunksum<<<dim3(nCh), dim3(256), 0, stream>>>(counts, bsum);
  k_chunkscan<<<dim3(1), dim3(64), 0, stream>>>(bsum, boff, row_start, N, nCh);
  k_scanapply<<<dim3(nCh), dim3(256), 0, stream>>>(counts, boff, row_start, cursor, N);
  k_scatter<<<dim3((E + 255) / 256), dim3(256), 0, stream>>>(ei32, combo, cursor, packed, E);

  const int wtBlocks = 64;  // 16384 threads for W1F/W2F words
  k_prep<<<dim3(wtBlocks + (N + 3) / 4), dim3(256), 0, stream>>>(
      cflt, x32, W1F, W2F, tblC, hb, N, wtBlocks);

  const float invN = 1.0f / (float)N;
  for (int l = 0; l < L; ++l) {
    k_agg<<<dim3((N + 15) / 16), dim3(256), 0, stream>>>(
        hb, row_start, packed, tblC, (u32*)zb, N);
    k_mlp<<<dim3(256), dim3(512), 0, stream>>>(
        zb, W1F, W2F, cB1, cB2, (u16*)act, statsC + (size_t)l * 32 * 256, N, nTiles);
    if (l < L - 1) {
      k_bnapply<<<dim3(1024), dim3(256), 0, stream>>>(
          act, statsC + (size_t)l * 32 * 256, cGamma + (size_t)l * 128,
          cBeta + (size_t)l * 128, invN, hb, N);
    }
  }
  k_final<<<dim3(1024), dim3(256), 0, stream>>>(
      act, statsC + (size_t)(L - 1) * 32 * 256, cGamma + (size_t)(L - 1) * 128,
      cBeta + (size_t)(L - 1) * 128, invN, dflags, d_out, N);
}